// Round 2
// baseline (276.685 us; speedup 1.0000x reference)
//
#include <hip/hip_runtime.h>
#include <math.h>

#define Hn 1024
#define Wn 2048
#define Bn 2
#define Cn 3
#define Pn 4
#define NSEAM (Pn - 1)
#define EPSf 1e-3f
#define THRf 0.5f
#define W_SEAMf 1.0f
#define W_GRADf 0.5f
#define W_LAPf 0.1f

__device__ __forceinline__ float rl1(float x) {
    return sqrtf(fmaf(x, x, EPSf * EPSf));
}

// One block per row h (all 3 seams). 256 threads, each owns 4 consecutive
// columns per half-row iteration. Writes per-row partials to ws[h*6 + p*2 +{0,1}]
// UNCONDITIONALLY (d_ws is poisoned 0xAA before every run — no memset needed).
__global__ __launch_bounds__(256) void seam_main(const float* __restrict__ procs,
                                                 const float* __restrict__ mask,
                                                 float* __restrict__ ws) {
    const int h = blockIdx.x;
    const size_t HW = (size_t)Hn * Wn;
    const size_t rowOff = (size_t)h * Wn;
    const size_t dAB = (size_t)(Bn * Cn) * HW;  // processes[p] -> processes[p+1]

    float wsum[NSEAM] = {0.f, 0.f, 0.f};
    float cnt[NSEAM]  = {0.f, 0.f, 0.f};

    const bool has_d = (h < Hn - 1);
    const bool has_u = (h > 0);

    #pragma unroll
    for (int it = 0; it < 2; ++it) {
        const int w0 = it * 1024 + (int)threadIdx.x * 4;

        // load all 4 mask planes for this row once
        float4 m[Pn];
        #pragma unroll
        for (int q = 0; q < Pn; ++q)
            m[q] = *(const float4*)(mask + (size_t)q * HW + rowOff + w0);

        #pragma unroll
        for (int p = 0; p < NSEAM; ++p) {
            bool bb[4];
            bb[0] = (m[p].x > THRf) && (m[p + 1].x > THRf);
            bb[1] = (m[p].y > THRf) && (m[p + 1].y > THRf);
            bb[2] = (m[p].z > THRf) && (m[p + 1].z > THRf);
            bb[3] = (m[p].w > THRf) && (m[p + 1].w > THRf);
            if (!(bb[0] | bb[1] | bb[2] | bb[3])) continue;

            cnt[p] += (float)bb[0] + (float)bb[1] + (float)bb[2] + (float)bb[3];

            const size_t baseA = (size_t)p * dAB + rowOff;
            float sj = 0.f, sg = 0.f, sl = 0.f;

            #pragma unroll
            for (int bc = 0; bc < Bn * Cn; ++bc) {
                const float* A  = procs + baseA + (size_t)bc * HW;
                const float* Bp = A + dAB;

                float4 ac = *(const float4*)(A + w0);
                float4 bcv = *(const float4*)(Bp + w0);
                float dc[4] = {ac.x - bcv.x, ac.y - bcv.y, ac.z - bcv.z, ac.w - bcv.w};

                float du[4] = {0.f, 0.f, 0.f, 0.f};
                float dd[4] = {0.f, 0.f, 0.f, 0.f};
                if (has_u) {
                    float4 au = *(const float4*)(A + w0 - Wn);
                    float4 bu = *(const float4*)(Bp + w0 - Wn);
                    du[0] = au.x - bu.x; du[1] = au.y - bu.y;
                    du[2] = au.z - bu.z; du[3] = au.w - bu.w;
                }
                if (has_d) {
                    float4 ad = *(const float4*)(A + w0 + Wn);
                    float4 bd = *(const float4*)(Bp + w0 + Wn);
                    dd[0] = ad.x - bd.x; dd[1] = ad.y - bd.y;
                    dd[2] = ad.z - bd.z; dd[3] = ad.w - bd.w;
                }

                float dl0 = (w0 > 0)      ? (A[w0 - 1] - Bp[w0 - 1]) : 0.f;
                float dr3 = (w0 + 4 < Wn) ? (A[w0 + 4] - Bp[w0 + 4]) : 0.f;
                float dl[4] = {dl0,   dc[0], dc[1], dc[2]};
                float dr[4] = {dc[1], dc[2], dc[3], dr3};

                #pragma unroll
                for (int e = 0; e < 4; ++e) {
                    if (bb[e]) {
                        sj += rl1(dc[e]);
                        // grad_h at h==H-1: diff of zero-padded rows -> rl1(0)=EPS
                        sg += has_d ? rl1(dd[e] - dc[e]) : EPSf;
                        sl += rl1(du[e] + dd[e] + dl[e] + dr[e] - 4.f * dc[e]);
                    }
                }
            }
            wsum[p] += W_SEAMf * sj + W_GRADf * sg + W_LAPf * sl;
        }
    }

    // wave-64 shuffle reduction of 6 accumulators
    #pragma unroll
    for (int off = 32; off > 0; off >>= 1) {
        #pragma unroll
        for (int p = 0; p < NSEAM; ++p) {
            wsum[p] += __shfl_down(wsum[p], off, 64);
            cnt[p]  += __shfl_down(cnt[p],  off, 64);
        }
    }
    __shared__ float sred[4][2 * NSEAM];
    const int wave = threadIdx.x >> 6;
    const int lane = threadIdx.x & 63;
    if (lane == 0) {
        #pragma unroll
        for (int p = 0; p < NSEAM; ++p) {
            sred[wave][2 * p]     = wsum[p];
            sred[wave][2 * p + 1] = cnt[p];
        }
    }
    __syncthreads();
    if (threadIdx.x == 0) {
        float* slot = ws + (size_t)h * (2 * NSEAM);
        #pragma unroll
        for (int p = 0; p < NSEAM; ++p) {
            slot[2 * p]     = sred[0][2 * p] + sred[1][2 * p] + sred[2][2 * p] + sred[3][2 * p];
            slot[2 * p + 1] = sred[0][2 * p + 1] + sred[1][2 * p + 1] + sred[2][2 * p + 1] + sred[3][2 * p + 1];
        }
    }
}

// One block, 256 threads: reduce the 1024 x 6 partials, divide per seam, sum.
__global__ __launch_bounds__(256) void seam_reduce(const float* __restrict__ ws,
                                                   float* __restrict__ out) {
    float ls[NSEAM] = {0.f, 0.f, 0.f};
    float lc[NSEAM] = {0.f, 0.f, 0.f};
    for (int r = threadIdx.x; r < Hn; r += 256) {
        const float* row = ws + (size_t)r * (2 * NSEAM);
        #pragma unroll
        for (int p = 0; p < NSEAM; ++p) {
            ls[p] += row[2 * p];
            lc[p] += row[2 * p + 1];
        }
    }
    #pragma unroll
    for (int off = 32; off > 0; off >>= 1) {
        #pragma unroll
        for (int p = 0; p < NSEAM; ++p) {
            ls[p] += __shfl_down(ls[p], off, 64);
            lc[p] += __shfl_down(lc[p], off, 64);
        }
    }
    __shared__ float sred[4][2 * NSEAM];
    const int wave = threadIdx.x >> 6;
    const int lane = threadIdx.x & 63;
    if (lane == 0) {
        #pragma unroll
        for (int p = 0; p < NSEAM; ++p) {
            sred[wave][2 * p]     = ls[p];
            sred[wave][2 * p + 1] = lc[p];
        }
    }
    __syncthreads();
    if (threadIdx.x == 0) {
        float acc = 0.f;
        #pragma unroll
        for (int p = 0; p < NSEAM; ++p) {
            float S = sred[0][2 * p] + sred[1][2 * p] + sred[2][2 * p] + sred[3][2 * p];
            float C = sred[0][2 * p + 1] + sred[1][2 * p + 1] + sred[2][2 * p + 1] + sred[3][2 * p + 1];
            acc += S / fmaxf(C, EPSf);
        }
        out[0] = acc;
    }
}

extern "C" void kernel_launch(void* const* d_in, const int* in_sizes, int n_in,
                              void* d_out, int out_size, void* d_ws, size_t ws_size,
                              hipStream_t stream) {
    const float* procs = (const float*)d_in[0];  // (P,B,C,H,W) fp32
    const float* mask  = (const float*)d_in[1];  // (P,1,H,W) fp32
    float* wsf = (float*)d_ws;

    seam_main<<<dim3(Hn), dim3(256), 0, stream>>>(procs, mask, wsf);
    seam_reduce<<<1, dim3(256), 0, stream>>>(wsf, (float*)d_out);
}